// Round 1
// baseline (239.861 us; speedup 1.0000x reference)
//
#include <hip/hip_runtime.h>
#include <stdint.h>

typedef float floatx4 __attribute__((ext_vector_type(4)));
typedef short short8 __attribute__((ext_vector_type(8)));

constexpr int I_SZ = 256, O_SZ = 256, NCOL = 512, B_SZ = 4096;
constexpr int KSTEPS = 264;           // 256 RBF steps (1 i each, K=64) + 8 silu steps
constexpr int SPC = 66;               // steps per K-chunk (4 chunks)
constexpr float GSTEP = 4.0f / 7.0f;  // linspace(-2,2,8) step
constexpr float NLOG2E = -1.44269504088896f;

// pack two fp32 -> two bf16 (truncate) in one v_perm_b32
__device__ __forceinline__ uint32_t pk_bf16(float lo, float hi) {
  return __builtin_amdgcn_perm(__float_as_uint(hi), __float_as_uint(lo), 0x07060302u);
}

__device__ __forceinline__ void gload_lds16(const void* g, void* l) {
  __builtin_amdgcn_global_load_lds((const __attribute__((address_space(1))) void*)g,
                                   (__attribute__((address_space(3))) void*)l,
                                   16, 0, 0);
}

// ---------------- weight packing: Wpack[kb][n][gp][e] bf16, gp = g ^ (n&7) ----------------
__global__ void pack_weights(const float* __restrict__ rw, const float* __restrict__ cw,
                             const float* __restrict__ swre, const float* __restrict__ swim,
                             short* __restrict__ wpack) {
  int idx = blockIdx.x * 256 + threadIdx.x;   // total 264*512*64
  int kb = idx >> 15;                          // / (512*64)
  int rem = idx & 32767;
  int n = rem >> 6;
  int j = rem & 63;
  int gp = j >> 3, e = j & 7;
  int g = gp ^ (n & 7);                        // XOR-swizzle of 16B groups
  int k = kb * 64 + g * 8 + e;
  int o = n >> 1, c = n & 1;
  float wv;
  if (k < 16384) {
    int i = k >> 6, r = k & 63, u = r >> 3, v = r & 7;
    const float* W = c ? cw : rw;
    wv = W[(((i * O_SZ) + o) * 8 + u) * 8 + v];
  } else {
    int kp = k - 16384; int i = kp >> 1; int ci = kp & 1;
    float a = swre[i * O_SZ + o], b = swim[i * O_SZ + o];
    wv = (c == 0) ? (ci == 0 ? a : -b) : (ci == 0 ? b : a);
  }
  uint32_t u32 = __float_as_uint(wv);          // RNE to bf16
  wpack[idx] = (short)((u32 + 0x7FFFu + ((u32 >> 16) & 1u)) >> 16);
}

// ---------------- bias column sums: bsum[n = o*2+c] = sum_i bias_c[i,o] ----------------
__global__ void bias_sums(const float* __restrict__ bre, const float* __restrict__ bim,
                          float* __restrict__ bsum) {
  int n = blockIdx.x * 256 + threadIdx.x;
  if (n >= NCOL) return;
  int o = n >> 1;
  const float* src = (n & 1) ? bim : bre;
  float s = 0.f;
  for (int i = 0; i < I_SZ; ++i) s += src[i * O_SZ + o];
  bsum[n] = s;
}

// ---------------- main fused GEMM: out[b][n] = sum_k A[b,k] * Wpack[k,n] (+bias) ----------------
// block: 128 rows x 128 cols, 4 waves (64x64 each), split-K = 4, atomicAdd epilogue.
__global__ __launch_bounds__(256, 2) void cvkan_gemm(
    const float* __restrict__ xre, const float* __restrict__ xim,
    const short* __restrict__ wpack, const float* __restrict__ bsum,
    float* __restrict__ out) {
  __shared__ __align__(16) short Bs[128 * 64];   // 16 KB, layout [col][gp][e], swizzled
  __shared__ __align__(16) char sA[16384];       // union: E fp32 [2][128][12] | silu bf16 tile [128][64]
  float* E = (float*)sA;
  short* As = (short*)sA;

  const int tid = threadIdx.x;
  const int bid = blockIdx.x;
  const int kch = bid >> 7;             // 0..3
  const int mn = bid & 127;
  const int mt = mn >> 2, nt = mn & 3;
  const int b0 = mt * 128, n0 = nt * 128;
  const int l = tid & 63, w = tid >> 6;
  const int wr = w >> 1, wc = w & 1;
  const int lm = l & 15, q = l >> 4;
  const int r_half = tid >> 1, h = tid & 1;

  floatx4 acc[4][4] = {};

  for (int s = kch * SPC; s < (kch + 1) * SPC; ++s) {
    // --- async stage B tile (16 KB): straight contiguous copy, swizzle is baked into Wpack ---
    {
      const short* src = wpack + (((size_t)s * NCOL + n0) << 6) + (tid << 3);
      short* ldst = Bs + (w << 9);   // wave-uniform LDS base; HW adds lane*16B
      gload_lds16(src,        ldst);
      gload_lds16(src + 2048, ldst + 2048);
      gload_lds16(src + 4096, ldst + 4096);
      gload_lds16(src + 6144, ldst + 6144);
    }

    if (s < 256) {
      // --- E tables for i = s: thread (row=tid>>1, h=tid&1) computes 8 exps ---
      const float* xs = h ? xim : xre;
      float x = xs[(size_t)(b0 + r_half) * I_SZ + s];
      float ev[8];
      #pragma unroll
      for (int g = 0; g < 8; ++g) {
        float d = x - (-2.0f + g * GSTEP);
        ev[g] = __builtin_amdgcn_exp2f(d * d * NLOG2E);
      }
      float* dst = E + h * 1536 + r_half * 12;   // row stride 12 floats (conflict padding)
      *(floatx4*)dst       = floatx4{ev[0], ev[1], ev[2], ev[3]};
      *(floatx4*)(dst + 4) = floatx4{ev[4], ev[5], ev[6], ev[7]};
    } else {
      // --- silu tile: A[b, 16384 + 2i + c] = silu(x_c[b,i]) ---
      int sl = s - 256;
      int i0 = sl * 32 + h * 16;
      const float* pr = xre + (size_t)(b0 + r_half) * I_SZ + i0;
      const float* pi = xim + (size_t)(b0 + r_half) * I_SZ + i0;
      float sr[16], si[16];
      #pragma unroll
      for (int m = 0; m < 16; ++m) {
        float a = pr[m], b = pi[m];
        sr[m] = a * __builtin_amdgcn_rcpf(1.f + __builtin_amdgcn_exp2f(a * NLOG2E));
        si[m] = b * __builtin_amdgcn_rcpf(1.f + __builtin_amdgcn_exp2f(b * NLOG2E));
      }
      #pragma unroll
      for (int gg = 0; gg < 4; ++gg) {
        int g = h * 4 + gg;
        uint4 val = make_uint4(pk_bf16(sr[gg*4+0], si[gg*4+0]),
                               pk_bf16(sr[gg*4+1], si[gg*4+1]),
                               pk_bf16(sr[gg*4+2], si[gg*4+2]),
                               pk_bf16(sr[gg*4+3], si[gg*4+3]));
        *(uint4*)(As + r_half * 64 + ((g ^ (r_half & 7)) << 3)) = val;
      }
    }

    __builtin_amdgcn_s_waitcnt(0);   // drain global_load_lds before barrier
    __syncthreads();

    // --- B fragments: B[k][n], n = lm, k = quad*8+j ---
    short8 bf[4][2];
    #pragma unroll
    for (int nn = 0; nn < 4; ++nn) {
      int col = wc * 64 + nn * 16 + lm;
      const short* bp = Bs + (col << 6);
      bf[nn][0] = *(const short8*)(bp + ((q       ^ (col & 7)) << 3));
      bf[nn][1] = *(const short8*)(bp + (((4 + q) ^ (col & 7)) << 3));
    }

    if (s < 256) {
      #pragma unroll
      for (int mm = 0; mm < 4; ++mm) {
        int row = wr * 64 + mm * 16 + lm;
        const float* em = E + 1536 + row * 12;
        floatx4 e0 = *(const floatx4*)em;        // eiv[0..3]
        floatx4 e1 = *(const floatx4*)(em + 4);  // eiv[4..7]
        float er0 = E[row * 12 + q];             // eru[q]     (kh=0: u=q)
        float er1 = E[row * 12 + q + 4];         // eru[q+4]   (kh=1: u=q+4)
        union { short8 v; uint32_t u[4]; } a0, a1;
        a0.u[0] = pk_bf16(er0 * e0.x, er0 * e0.y);
        a0.u[1] = pk_bf16(er0 * e0.z, er0 * e0.w);
        a0.u[2] = pk_bf16(er0 * e1.x, er0 * e1.y);
        a0.u[3] = pk_bf16(er0 * e1.z, er0 * e1.w);
        a1.u[0] = pk_bf16(er1 * e0.x, er1 * e0.y);
        a1.u[1] = pk_bf16(er1 * e0.z, er1 * e0.w);
        a1.u[2] = pk_bf16(er1 * e1.x, er1 * e1.y);
        a1.u[3] = pk_bf16(er1 * e1.z, er1 * e1.w);
        #pragma unroll
        for (int nn = 0; nn < 4; ++nn) {
          acc[mm][nn] = __builtin_amdgcn_mfma_f32_16x16x32_bf16(a0.v, bf[nn][0], acc[mm][nn], 0, 0, 0);
          acc[mm][nn] = __builtin_amdgcn_mfma_f32_16x16x32_bf16(a1.v, bf[nn][1], acc[mm][nn], 0, 0, 0);
        }
      }
    } else {
      #pragma unroll
      for (int mm = 0; mm < 4; ++mm) {
        int row = wr * 64 + mm * 16 + lm;
        const short* ap = As + (row << 6);
        short8 a0 = *(const short8*)(ap + ((q       ^ (row & 7)) << 3));
        short8 a1 = *(const short8*)(ap + (((4 + q) ^ (row & 7)) << 3));
        #pragma unroll
        for (int nn = 0; nn < 4; ++nn) {
          acc[mm][nn] = __builtin_amdgcn_mfma_f32_16x16x32_bf16(a0, bf[nn][0], acc[mm][nn], 0, 0, 0);
          acc[mm][nn] = __builtin_amdgcn_mfma_f32_16x16x32_bf16(a1, bf[nn][1], acc[mm][nn], 0, 0, 0);
        }
      }
    }
    __syncthreads();
  }

  // --- epilogue: C/D layout col=lane&15, row=quad*4+reg; bias added by chunk-3 only ---
  #pragma unroll
  for (int nn = 0; nn < 4; ++nn) {
    int col = n0 + wc * 64 + nn * 16 + lm;
    float bv = (kch == 3) ? bsum[col] : 0.0f;
    #pragma unroll
    for (int mm = 0; mm < 4; ++mm) {
      int row0 = b0 + wr * 64 + mm * 16 + (q << 2);
      #pragma unroll
      for (int r2 = 0; r2 < 4; ++r2)
        atomicAdd(out + (size_t)(row0 + r2) * NCOL + col, acc[mm][nn][r2] + bv);
    }
  }
}

extern "C" void kernel_launch(void* const* d_in, const int* in_sizes, int n_in,
                              void* d_out, int out_size, void* d_ws, size_t ws_size,
                              hipStream_t stream) {
  const float* xre  = (const float*)d_in[0];
  const float* xim  = (const float*)d_in[1];
  const float* rw   = (const float*)d_in[2];
  const float* cw   = (const float*)d_in[3];
  const float* swre = (const float*)d_in[4];
  const float* swim = (const float*)d_in[5];
  const float* bre  = (const float*)d_in[6];
  const float* bim  = (const float*)d_in[7];
  float* out = (float*)d_out;

  short* wpack = (short*)d_ws;                                         // 264*512*64 bf16 = 16.5 MiB
  float* bsum  = (float*)((char*)d_ws + (size_t)KSTEPS * NCOL * 64 * 2);

  hipMemsetAsync(d_out, 0, (size_t)B_SZ * NCOL * sizeof(float), stream);
  pack_weights<<<(KSTEPS * NCOL * 64) / 256, 256, 0, stream>>>(rw, cw, swre, swim, wpack);
  bias_sums<<<2, 256, 0, stream>>>(bre, bim, bsum);
  cvkan_gemm<<<512, 256, 0, stream>>>(xre, xim, wpack, bsum, out);
}

// Round 2
// 223.560 us; speedup vs baseline: 1.0729x; 1.0729x over previous
//
#include <hip/hip_runtime.h>
#include <stdint.h>

typedef float floatx4 __attribute__((ext_vector_type(4)));
typedef short short8 __attribute__((ext_vector_type(8)));

constexpr int I_SZ = 256, O_SZ = 256, NCOL = 512, B_SZ = 4096;
constexpr int KSTEPS = 264;           // 256 RBF steps (1 i each, K=64) + 8 silu steps
constexpr int SPC = 33;               // steps per K-chunk (8 chunks)
constexpr float GSTEP = 4.0f / 7.0f;  // linspace(-2,2,8) step
constexpr float NLOG2E = -1.44269504088896f;

// pack two fp32 -> two bf16 (truncate) in one v_perm_b32
__device__ __forceinline__ uint32_t pk_bf16(float lo, float hi) {
  return __builtin_amdgcn_perm(__float_as_uint(hi), __float_as_uint(lo), 0x07060302u);
}
__device__ __forceinline__ short rne_bf16(float f) {
  uint32_t u = __float_as_uint(f);
  return (short)((u + 0x7FFFu + ((u >> 16) & 1u)) >> 16);
}

__device__ __forceinline__ void gload_lds16(const void* g, void* l) {
  __builtin_amdgcn_global_load_lds((const __attribute__((address_space(1))) void*)g,
                                   (__attribute__((address_space(3))) void*)l,
                                   16, 0, 0);
}

__device__ __forceinline__ float silu_f(float a) {
  return a * __builtin_amdgcn_rcpf(1.f + __builtin_amdgcn_exp2f(a * NLOG2E));
}

// ---------------- weight packing: Wpack[kb][n][gp][e] bf16, gp = g ^ (n&7); 8 elems/thread ----------------
__global__ void pack_weights(const float* __restrict__ rw, const float* __restrict__ cw,
                             const float* __restrict__ swre, const float* __restrict__ swim,
                             short* __restrict__ wpack) {
  int idx = blockIdx.x * 256 + threadIdx.x;   // enumerates (kb, n, gp): 264*512*8
  int kb = idx >> 12;                          // / (512*8)
  int rem = idx & 4095;
  int n = rem >> 3, gp = rem & 7;
  int g = gp ^ (n & 7);                        // XOR-swizzle of 16B groups
  int o = n >> 1, c = n & 1;
  float w[8];
  if (kb < 256) {
    const float* W = (c ? cw : rw) + (((size_t)kb * O_SZ + o) << 6) + (g << 3);
    float4 a = *(const float4*)W;
    float4 b = *(const float4*)(W + 4);
    w[0] = a.x; w[1] = a.y; w[2] = a.z; w[3] = a.w;
    w[4] = b.x; w[5] = b.y; w[6] = b.z; w[7] = b.w;
  } else {
    int kp0 = ((kb - 256) << 6) + (g << 3);
    #pragma unroll
    for (int e = 0; e < 8; ++e) {
      int kp = kp0 + e, i = kp >> 1, ci = kp & 1;
      float a = swre[i * O_SZ + o], b = swim[i * O_SZ + o];
      w[e] = (c == 0) ? (ci == 0 ? a : -b) : (ci == 0 ? b : a);
    }
  }
  uint32_t h[8];
  #pragma unroll
  for (int e = 0; e < 8; ++e) h[e] = (uint32_t)(uint16_t)rne_bf16(w[e]);
  uint4 val = make_uint4(h[0] | (h[1] << 16), h[2] | (h[3] << 16),
                         h[4] | (h[5] << 16), h[6] | (h[7] << 16));
  *(uint4*)(wpack + (size_t)idx * 8) = val;
}

// ---------------- bias column sums: bsum[n = o*2+c] = sum_i bias_c[i,o]; one wave per n ----------------
__global__ void bias_sums(const float* __restrict__ bre, const float* __restrict__ bim,
                          float* __restrict__ bsum) {
  int n = blockIdx.x, o = n >> 1, l = threadIdx.x;
  const float* src = ((n & 1) ? bim : bre) + o;
  float s = 0.f;
  #pragma unroll
  for (int a = 0; a < 4; ++a) s += src[(size_t)(a * 64 + l) * O_SZ];
  #pragma unroll
  for (int off = 32; off; off >>= 1) s += __shfl_down(s, off, 64);
  if (l == 0) bsum[n] = s;
}

// ---------------- main fused GEMM: out[b][n] = sum_k A[b,k] * Wpack[k,n] (+bias) ----------------
// block: 128 rows x 128 cols, 4 waves (64x64 each), split-K = 8, atomicAdd epilogue.
// A tile built cooperatively in LDS (bf16, XOR-swizzled groups) — no per-wave duplication.
__global__ __launch_bounds__(256, 4) void cvkan_gemm(
    const float* __restrict__ xre, const float* __restrict__ xim,
    const short* __restrict__ wpack, const float* __restrict__ bsum,
    float* __restrict__ out) {
  __shared__ __align__(16) short Bs[128 * 64];   // 16 KB, [col][gp][e], gp = g ^ (col&7)
  __shared__ __align__(16) short As[128 * 64];   // 16 KB, [row][gp][e], gp = g ^ (row&7)

  const int tid = threadIdx.x;
  const int bid = blockIdx.x;
  const int kch = bid & 7;              // K-chunk: XCD-aligned so each XCD re-reads one 2MB wpack slice
  const int mn = bid >> 3;
  const int mt = mn >> 2, nt = mn & 3;
  const int b0 = mt * 128, n0 = nt * 128;
  const int l = tid & 63, w = tid >> 6;
  const int wr = w >> 1, wc = w & 1;
  const int lm = l & 15, q = l >> 4;
  const int r = tid >> 1, h = tid & 1;  // A-tile build: row r, u/i-half h

  floatx4 acc[4][4] = {};

  for (int s = kch * SPC; s < (kch + 1) * SPC; ++s) {
    // --- async stage B tile (16 KB): contiguous copy, swizzle baked into Wpack ---
    {
      const short* src = wpack + (((size_t)s * NCOL + n0) << 6) + (tid << 3);
      short* ldst = Bs + (w << 9);   // wave-uniform base; HW adds lane*16B
      gload_lds16(src,        ldst);
      gload_lds16(src + 2048, ldst + 2048);
      gload_lds16(src + 4096, ldst + 4096);
      gload_lds16(src + 6144, ldst + 6144);
    }

    // --- build A tile cooperatively: thread (r, h) writes groups g = 4h..4h+3 of row r ---
    if (s < 256) {
      float xr = xre[(size_t)(b0 + r) * I_SZ + s];
      float xi = xim[(size_t)(b0 + r) * I_SZ + s];
      float eiv[8];
      #pragma unroll
      for (int v = 0; v < 8; ++v) {
        float d = xi - (-2.0f + v * GSTEP);
        eiv[v] = __builtin_amdgcn_exp2f(d * d * NLOG2E);
      }
      #pragma unroll
      for (int uu = 0; uu < 4; ++uu) {
        int u = h * 4 + uu;
        float d = xr - (-2.0f + u * GSTEP);
        float er = __builtin_amdgcn_exp2f(d * d * NLOG2E);
        uint4 val = make_uint4(pk_bf16(er * eiv[0], er * eiv[1]),
                               pk_bf16(er * eiv[2], er * eiv[3]),
                               pk_bf16(er * eiv[4], er * eiv[5]),
                               pk_bf16(er * eiv[6], er * eiv[7]));
        *(uint4*)(As + (r << 6) + ((u ^ (r & 7)) << 3)) = val;
      }
    } else {
      int sl = s - 256;                // silu step: A[b, 16384+2i+c] = silu(x_c[b,i])
      #pragma unroll
      for (int gg = 0; gg < 4; ++gg) {
        int g = h * 4 + gg;
        const float* pr = xre + (size_t)(b0 + r) * I_SZ + (sl << 5) + (g << 2);
        const float* pi = xim + (size_t)(b0 + r) * I_SZ + (sl << 5) + (g << 2);
        uint4 val = make_uint4(pk_bf16(silu_f(pr[0]), silu_f(pi[0])),
                               pk_bf16(silu_f(pr[1]), silu_f(pi[1])),
                               pk_bf16(silu_f(pr[2]), silu_f(pi[2])),
                               pk_bf16(silu_f(pr[3]), silu_f(pi[3])));
        *(uint4*)(As + (r << 6) + ((g ^ (r & 7)) << 3)) = val;
      }
    }

    __builtin_amdgcn_s_waitcnt(0);   // drain global_load_lds before barrier
    __syncthreads();

    // --- B fragments: B[k][n], n = lm, k = q*8+j (and +32) ---
    short8 bf[4][2];
    #pragma unroll
    for (int nn = 0; nn < 4; ++nn) {
      int col = wc * 64 + nn * 16 + lm;
      const short* bp = Bs + (col << 6);
      bf[nn][0] = *(const short8*)(bp + ((q       ^ (col & 7)) << 3));
      bf[nn][1] = *(const short8*)(bp + (((q + 4) ^ (col & 7)) << 3));
    }
    #pragma unroll
    for (int mm = 0; mm < 4; ++mm) {
      int row = wr * 64 + mm * 16 + lm;
      const short* ap = As + (row << 6);
      short8 a0 = *(const short8*)(ap + ((q       ^ (row & 7)) << 3));
      short8 a1 = *(const short8*)(ap + (((q + 4) ^ (row & 7)) << 3));
      #pragma unroll
      for (int nn = 0; nn < 4; ++nn) {
        acc[mm][nn] = __builtin_amdgcn_mfma_f32_16x16x32_bf16(a0, bf[nn][0], acc[mm][nn], 0, 0, 0);
        acc[mm][nn] = __builtin_amdgcn_mfma_f32_16x16x32_bf16(a1, bf[nn][1], acc[mm][nn], 0, 0, 0);
      }
    }
    __syncthreads();
  }

  // --- epilogue: C/D layout col=lane&15, row=q*4+reg; bias added by chunk-7 only ---
  #pragma unroll
  for (int nn = 0; nn < 4; ++nn) {
    int col = n0 + wc * 64 + nn * 16 + lm;
    float bv = (kch == 7) ? bsum[col] : 0.0f;
    #pragma unroll
    for (int mm = 0; mm < 4; ++mm) {
      int row0 = b0 + wr * 64 + mm * 16 + (q << 2);
      #pragma unroll
      for (int r2 = 0; r2 < 4; ++r2)
        atomicAdd(out + (size_t)(row0 + r2) * NCOL + col, acc[mm][nn][r2] + bv);
    }
  }
}

extern "C" void kernel_launch(void* const* d_in, const int* in_sizes, int n_in,
                              void* d_out, int out_size, void* d_ws, size_t ws_size,
                              hipStream_t stream) {
  const float* xre  = (const float*)d_in[0];
  const float* xim  = (const float*)d_in[1];
  const float* rw   = (const float*)d_in[2];
  const float* cw   = (const float*)d_in[3];
  const float* swre = (const float*)d_in[4];
  const float* swim = (const float*)d_in[5];
  const float* bre  = (const float*)d_in[6];
  const float* bim  = (const float*)d_in[7];
  float* out = (float*)d_out;

  short* wpack = (short*)d_ws;                                         // 264*512*64 bf16 = 16.5 MiB
  float* bsum  = (float*)((char*)d_ws + (size_t)KSTEPS * NCOL * 64 * 2);

  hipMemsetAsync(d_out, 0, (size_t)B_SZ * NCOL * sizeof(float), stream);
  pack_weights<<<(KSTEPS * NCOL * 8) / 256, 256, 0, stream>>>(rw, cw, swre, swim, wpack);
  bias_sums<<<NCOL, 64, 0, stream>>>(bre, bim, bsum);
  cvkan_gemm<<<1024, 256, 0, stream>>>(xre, xim, wpack, bsum, out);
}

// Round 3
// 205.899 us; speedup vs baseline: 1.1649x; 1.0858x over previous
//
#include <hip/hip_runtime.h>
#include <hip/hip_fp16.h>
#include <stdint.h>

typedef float floatx4 __attribute__((ext_vector_type(4)));
typedef short short8 __attribute__((ext_vector_type(8)));

constexpr int I_SZ = 256, O_SZ = 256, NCOL = 512, B_SZ = 4096;
constexpr int KSTEPS = 264;           // 256 RBF steps + 8 silu steps
constexpr float GSTEP = 4.0f / 7.0f;  // linspace(-2,2,8) step
constexpr float NLOG2E = -1.44269504088896f;

// pack two fp32 -> two bf16 (truncate) in one v_perm_b32
__device__ __forceinline__ uint32_t pk_bf16(float lo, float hi) {
  return __builtin_amdgcn_perm(__float_as_uint(hi), __float_as_uint(lo), 0x07060302u);
}
__device__ __forceinline__ short rne_bf16(float f) {
  uint32_t u = __float_as_uint(f);
  return (short)((u + 0x7FFFu + ((u >> 16) & 1u)) >> 16);
}

__device__ __forceinline__ void gload_lds16(const void* g, void* l) {
  __builtin_amdgcn_global_load_lds((const __attribute__((address_space(1))) void*)g,
                                   (__attribute__((address_space(3))) void*)l,
                                   16, 0, 0);
}

__device__ __forceinline__ float silu_f(float a) {
  return a * __builtin_amdgcn_rcpf(1.f + __builtin_amdgcn_exp2f(a * NLOG2E));
}

// ---------------- weight packing: Wpack[kb][n][gp][e] bf16, gp = g ^ (n&7); 8 elems/thread ----------------
__global__ void pack_weights(const float* __restrict__ rw, const float* __restrict__ cw,
                             const float* __restrict__ swre, const float* __restrict__ swim,
                             short* __restrict__ wpack) {
  int idx = blockIdx.x * 256 + threadIdx.x;   // enumerates (kb, n, gp): 264*512*8
  int kb = idx >> 12;
  int rem = idx & 4095;
  int n = rem >> 3, gp = rem & 7;
  int g = gp ^ (n & 7);
  int o = n >> 1, c = n & 1;
  float w[8];
  if (kb < 256) {
    const float* W = (c ? cw : rw) + (((size_t)kb * O_SZ + o) << 6) + (g << 3);
    float4 a = *(const float4*)W;
    float4 b = *(const float4*)(W + 4);
    w[0] = a.x; w[1] = a.y; w[2] = a.z; w[3] = a.w;
    w[4] = b.x; w[5] = b.y; w[6] = b.z; w[7] = b.w;
  } else {
    int kp0 = ((kb - 256) << 6) + (g << 3);
    #pragma unroll
    for (int e = 0; e < 8; ++e) {
      int kp = kp0 + e, i = kp >> 1, ci = kp & 1;
      float a = swre[i * O_SZ + o], b = swim[i * O_SZ + o];
      w[e] = (c == 0) ? (ci == 0 ? a : -b) : (ci == 0 ? b : a);
    }
  }
  uint32_t h[8];
  #pragma unroll
  for (int e = 0; e < 8; ++e) h[e] = (uint32_t)(uint16_t)rne_bf16(w[e]);
  uint4 val = make_uint4(h[0] | (h[1] << 16), h[2] | (h[3] << 16),
                         h[4] | (h[5] << 16), h[6] | (h[7] << 16));
  *(uint4*)(wpack + (size_t)idx * 8) = val;
}

// ---------------- x transpose: xT[c][i][b] fp16 from x[b][i] fp32 ----------------
__global__ void transpose_x(const float* __restrict__ xre, const float* __restrict__ xim,
                            __half* __restrict__ xT) {
  __shared__ float tile[64][65];
  int bt = blockIdx.x & 63;           // b-tile (4096/64)
  int it = (blockIdx.x >> 6) & 3;     // i-tile (256/64)
  int c  = blockIdx.x >> 8;           // plane
  const float* src = (c ? xim : xre);
  int b0 = bt << 6, i0 = it << 6;
  int t = threadIdx.x;
  int il = t & 63, bh = t >> 6;       // load: consecutive t -> consecutive i (coalesced)
  #pragma unroll
  for (int k = 0; k < 16; ++k) {
    int bl = bh + (k << 2);
    tile[bl][il] = src[(size_t)(b0 + bl) * I_SZ + i0 + il];
  }
  __syncthreads();
  int bl2 = t & 63, ih = t >> 6;      // store: consecutive t -> consecutive b (coalesced)
  __half* dst = xT + ((size_t)c * I_SZ + i0) * B_SZ + b0;
  #pragma unroll
  for (int k = 0; k < 16; ++k) {
    int il2 = ih + (k << 2);
    dst[(size_t)il2 * B_SZ + bl2] = __float2half(tile[bl2][il2]);
  }
}

// ---------------- bias column sums ----------------
__global__ void bias_sums(const float* __restrict__ bre, const float* __restrict__ bim,
                          float* __restrict__ bsum) {
  int n = blockIdx.x, o = n >> 1, l = threadIdx.x;
  const float* src = ((n & 1) ? bim : bre) + o;
  float s = 0.f;
  #pragma unroll
  for (int a = 0; a < 4; ++a) s += src[(size_t)(a * 64 + l) * O_SZ];
  #pragma unroll
  for (int off = 32; off; off >>= 1) s += __shfl_down(s, off, 64);
  if (l == 0) bsum[n] = s;
}

// ---------------- main fused GEMM ----------------
// block: 128 rows x 128 cols, 4 waves (64x64), split-K = 8 chunks of (32 RBF + 1 silu) steps.
__global__ __launch_bounds__(256, 4) void cvkan_gemm(
    const float* __restrict__ xre, const float* __restrict__ xim,
    const __half* __restrict__ xT,
    const short* __restrict__ wpack, const float* __restrict__ bsum,
    float* __restrict__ out) {
  __shared__ __align__(16) short Bs[128 * 64];   // [col][gp][e], gp = g ^ (col&7)
  __shared__ __align__(16) short As[128 * 64];   // [row][gp][e], gp = g ^ (row&7)

  const int tid = threadIdx.x;
  const int bid = blockIdx.x;
  const int kch = bid & 7;              // K-chunk; XCD-aligned -> each XCD re-reads one ~2MB wpack slice
  const int mn = bid >> 3;
  const int mt = mn >> 2, nt = mn & 3;
  const int b0 = mt * 128, n0 = nt * 128;
  const int l = tid & 63, w = tid >> 6;
  const int wr = w >> 1, wc = w & 1;
  const int lm = l & 15, q = l >> 4;
  const int r = tid >> 1, h = tid & 1;  // A-build: row r, half h

  const __half* xTre = xT;
  const __half* xTim = xT + (size_t)I_SZ * B_SZ;

  floatx4 acc[4][4] = {};

  for (int j = 0; j < 33; ++j) {
    const int s = (j < 32) ? (kch * 32 + j) : (256 + kch);

    // hoisted coalesced x loads for the RBF A-build (L1-resident via transpose)
    float xr = 0.f, xi = 0.f;
    if (j < 32) {
      xr = __half2float(xTre[(size_t)s * B_SZ + b0 + r]);
      xi = __half2float(xTim[(size_t)s * B_SZ + b0 + r]);
    }

    // --- async stage B tile (16 KB): contiguous copy, swizzle baked into Wpack ---
    {
      const short* src = wpack + (((size_t)s * NCOL + n0) << 6) + (tid << 3);
      short* ldst = Bs + (w << 9);   // wave-uniform base; HW adds lane*16B
      gload_lds16(src,        ldst);
      gload_lds16(src + 2048, ldst + 2048);
      gload_lds16(src + 4096, ldst + 4096);
      gload_lds16(src + 6144, ldst + 6144);
    }

    // --- build A tile cooperatively ---
    if (j < 32) {
      float eiv[8];
      #pragma unroll
      for (int v = 0; v < 8; ++v) {
        float d = xi - (-2.0f + v * GSTEP);
        eiv[v] = __builtin_amdgcn_exp2f(d * d * NLOG2E);
      }
      #pragma unroll
      for (int uu = 0; uu < 4; ++uu) {
        int u = h * 4 + uu;
        float d = xr - (-2.0f + u * GSTEP);
        float er = __builtin_amdgcn_exp2f(d * d * NLOG2E);
        uint4 val = make_uint4(pk_bf16(er * eiv[0], er * eiv[1]),
                               pk_bf16(er * eiv[2], er * eiv[3]),
                               pk_bf16(er * eiv[4], er * eiv[5]),
                               pk_bf16(er * eiv[6], er * eiv[7]));
        *(uint4*)(As + (r << 6) + ((u ^ (r & 7)) << 3)) = val;
      }
    } else {
      int sl = kch;                    // silu step: A[b, 16384+2i+c] = silu(x_c[b,i])
      #pragma unroll
      for (int gg = 0; gg < 4; ++gg) {
        int g = h * 4 + gg;
        const float* pr = xre + (size_t)(b0 + r) * I_SZ + (sl << 5) + (g << 2);
        const float* pi = xim + (size_t)(b0 + r) * I_SZ + (sl << 5) + (g << 2);
        uint4 val = make_uint4(pk_bf16(silu_f(pr[0]), silu_f(pi[0])),
                               pk_bf16(silu_f(pr[1]), silu_f(pi[1])),
                               pk_bf16(silu_f(pr[2]), silu_f(pi[2])),
                               pk_bf16(silu_f(pr[3]), silu_f(pi[3])));
        *(uint4*)(As + (r << 6) + ((g ^ (r & 7)) << 3)) = val;
      }
    }

    __builtin_amdgcn_s_waitcnt(0);   // drain global_load_lds before barrier
    __syncthreads();

    // --- B fragments: n = lm, k = q*8+j (and +32) ---
    short8 bf[4][2];
    #pragma unroll
    for (int nn = 0; nn < 4; ++nn) {
      int col = wc * 64 + nn * 16 + lm;
      const short* bp = Bs + (col << 6);
      bf[nn][0] = *(const short8*)(bp + ((q       ^ (col & 7)) << 3));
      bf[nn][1] = *(const short8*)(bp + (((q + 4) ^ (col & 7)) << 3));
    }
    #pragma unroll
    for (int mm = 0; mm < 4; ++mm) {
      int row = wr * 64 + mm * 16 + lm;
      const short* ap = As + (row << 6);
      short8 a0 = *(const short8*)(ap + ((q       ^ (row & 7)) << 3));
      short8 a1 = *(const short8*)(ap + (((q + 4) ^ (row & 7)) << 3));
      #pragma unroll
      for (int nn = 0; nn < 4; ++nn) {
        acc[mm][nn] = __builtin_amdgcn_mfma_f32_16x16x32_bf16(a0, bf[nn][0], acc[mm][nn], 0, 0, 0);
        acc[mm][nn] = __builtin_amdgcn_mfma_f32_16x16x32_bf16(a1, bf[nn][1], acc[mm][nn], 0, 0, 0);
      }
    }
    __syncthreads();
  }

  // --- epilogue: C/D layout col=lane&15, row=q*4+reg; bias added by chunk-7 only ---
  #pragma unroll
  for (int nn = 0; nn < 4; ++nn) {
    int col = n0 + wc * 64 + nn * 16 + lm;
    float bv = (kch == 7) ? bsum[col] : 0.0f;
    #pragma unroll
    for (int mm = 0; mm < 4; ++mm) {
      int row0 = b0 + wr * 64 + mm * 16 + (q << 2);
      #pragma unroll
      for (int r2 = 0; r2 < 4; ++r2)
        atomicAdd(out + (size_t)(row0 + r2) * NCOL + col, acc[mm][nn][r2] + bv);
    }
  }
}

extern "C" void kernel_launch(void* const* d_in, const int* in_sizes, int n_in,
                              void* d_out, int out_size, void* d_ws, size_t ws_size,
                              hipStream_t stream) {
  const float* xre  = (const float*)d_in[0];
  const float* xim  = (const float*)d_in[1];
  const float* rw   = (const float*)d_in[2];
  const float* cw   = (const float*)d_in[3];
  const float* swre = (const float*)d_in[4];
  const float* swim = (const float*)d_in[5];
  const float* bre  = (const float*)d_in[6];
  const float* bim  = (const float*)d_in[7];
  float* out = (float*)d_out;

  size_t wpack_bytes = (size_t)KSTEPS * NCOL * 64 * 2;   // 16.5 MiB
  short* wpack = (short*)d_ws;
  float* bsum  = (float*)((char*)d_ws + wpack_bytes);
  __half* xT   = (__half*)((char*)d_ws + wpack_bytes + 2048);  // 2 planes * 256*4096 fp16 = 4 MiB

  hipMemsetAsync(d_out, 0, (size_t)B_SZ * NCOL * sizeof(float), stream);
  pack_weights<<<(KSTEPS * NCOL * 8) / 256, 256, 0, stream>>>(rw, cw, swre, swim, wpack);
  transpose_x<<<512, 256, 0, stream>>>(xre, xim, xT);
  bias_sums<<<NCOL, 64, 0, stream>>>(bre, bim, bsum);
  cvkan_gemm<<<1024, 256, 0, stream>>>(xre, xim, xT, wpack, bsum, out);
}